// Round 1
// baseline (6514.870 us; speedup 1.0000x reference)
//
#include <hip/hip_runtime.h>

#define DEV __device__ __forceinline__

namespace {

constexpr int B_ = 16, N_ = 4096, S_ = 512, CF_ = 64, CIN0 = 67;
constexpr float EPS_ = 1e-5f;

// ---- ws layout (float units) ----
constexpr int FPSIDX_OFF = 0;                        // 8192 ints
constexpr int IDX0_OFF   = FPSIDX_OFF + 8192;        // B*S*32 ints
constexpr int IDX1_OFF   = IDX0_OFF + B_ * S_ * 32;  // B*S*64 ints
constexpr int STATS_OFF  = IDX1_OFF + B_ * S_ * 64;  // 6 slots * 256 f
constexpr int AC_OFF     = STATS_OFF + 6 * 256;      // 6 slots * 256 f
constexpr int WT00_OFF   = AC_OFF + 6 * 256;
constexpr int WT01_OFF   = WT00_OFF + 64 * 67;
constexpr int WT02_OFF   = WT01_OFF + 64 * 64;
constexpr int WT10_OFF   = WT02_OFF + 128 * 64;
constexpr int WT11_OFF   = WT10_OFF + 64 * 67;
constexpr int WT12_OFF   = WT11_OFF + 96 * 64;
constexpr int MAXT_OFF   = WT12_OFF + 128 * 96;      // 8192*128 f
// total ≈ 1.89M floats ≈ 7.6 MB

DEV int rfl(int x) { return __builtin_amdgcn_readfirstlane(x); }

// ===================== FPS =====================
__global__ __launch_bounds__(1024) void fps_kernel(const float* __restrict__ xyz,
                                                   int* __restrict__ fps_idx,
                                                   float* __restrict__ newxyz) {
  __shared__ float px[N_], py[N_], pz[N_];
  __shared__ float swv[16];
  __shared__ int   swi[16];
  __shared__ int   s_last;
  const int b = blockIdx.x, t = threadIdx.x;
  const float* xb = xyz + (size_t)b * N_ * 3;
  for (int i = t; i < N_; i += 1024) {
    px[i] = xb[i * 3 + 0];
    py[i] = xb[i * 3 + 1];
    pz[i] = xb[i * 3 + 2];
  }
  __syncthreads();
  float dr[4] = {1e10f, 1e10f, 1e10f, 1e10f};
  int last = 0;
  if (t == 0) {
    fps_idx[b * S_ + 0] = 0;
    newxyz[(size_t)(b * S_ + 0) * 3 + 0] = px[0];
    newxyz[(size_t)(b * S_ + 0) * 3 + 1] = py[0];
    newxyz[(size_t)(b * S_ + 0) * 3 + 2] = pz[0];
  }
  for (int it = 1; it < S_; ++it) {
    const float cx = px[last], cy = py[last], cz = pz[last];
    float bv = -1.0f;
    int bi = 0x7fffffff;
#pragma unroll
    for (int j = 0; j < 4; ++j) {
      const int i = t + j * 1024;
      float d;
      {
#pragma clang fp contract(off)
        float dx = px[i] - cx, dy = py[i] - cy, dz = pz[i] - cz;
        d = (dx * dx + dy * dy) + dz * dz;
      }
      float dm = dr[j] < d ? dr[j] : d;
      dr[j] = dm;
      if (dm > bv) { bv = dm; bi = i; }  // strict > keeps lowest index (i ascending)
    }
#pragma unroll
    for (int m = 1; m < 64; m <<= 1) {
      float ov = __shfl_xor(bv, m);
      int   oi = __shfl_xor(bi, m);
      if (ov > bv || (ov == bv && oi < bi)) { bv = ov; bi = oi; }
    }
    if ((t & 63) == 0) { swv[t >> 6] = bv; swi[t >> 6] = bi; }
    __syncthreads();
    if (t < 64) {
      float v2 = (t < 16) ? swv[t] : -1.0f;
      int   i2 = (t < 16) ? swi[t] : 0x7fffffff;
#pragma unroll
      for (int m = 1; m < 16; m <<= 1) {
        float ov = __shfl_xor(v2, m);
        int   oi = __shfl_xor(i2, m);
        if (ov > v2 || (ov == v2 && oi < i2)) { v2 = ov; i2 = oi; }
      }
      if (t == 0) {
        s_last = i2;
        fps_idx[b * S_ + it] = i2;
        newxyz[(size_t)(b * S_ + it) * 3 + 0] = px[i2];
        newxyz[(size_t)(b * S_ + it) * 3 + 1] = py[i2];
        newxyz[(size_t)(b * S_ + it) * 3 + 2] = pz[i2];
      }
    }
    __syncthreads();
    last = s_last;
  }
}

// ===================== Ball query =====================
template <int NS>
__global__ __launch_bounds__(256) void ballq_kernel(const float* __restrict__ xyz,
                                                    const float* __restrict__ newxyz,
                                                    int* __restrict__ idx, float r2) {
  __shared__ int sbuf[4][NS];
  const int wiv = threadIdx.x >> 6;
  const int lane = threadIdx.x & 63;
  const int cs = blockIdx.x * 4 + wiv;  // grid is exact: 2048*4 == 8192
  const int b = cs >> 9;
  const float cx = newxyz[(size_t)cs * 3 + 0];
  const float cy = newxyz[(size_t)cs * 3 + 1];
  const float cz = newxyz[(size_t)cs * 3 + 2];
  const float* xb = xyz + (size_t)b * N_ * 3;
  int* my = sbuf[wiv];
  int cnt = 0;
  for (int base = 0; base < N_; base += 64) {
    if (cnt >= NS) break;  // cnt is wave-uniform
    const int i = base + lane;
    float d;
    {
#pragma clang fp contract(off)
      float dx = xb[i * 3 + 0] - cx, dy = xb[i * 3 + 1] - cy, dz = xb[i * 3 + 2] - cz;
      d = (dx * dx + dy * dy) + dz * dz;
    }
    const bool q = d < r2;
    const unsigned long long m = __ballot(q);
    if (q) {
      int pos = cnt + __popcll(m & ((1ull << lane) - 1ull));
      if (pos < NS) my[pos] = i;
    }
    cnt += __popcll(m);
  }
  __syncthreads();
  const int c = cnt < NS ? cnt : NS;
  const int first = my[0];  // center itself always qualifies (d=0)
  for (int j = lane; j < NS; j += 64) idx[(size_t)cs * NS + j] = (j < c) ? my[j] : first;
}

// ===================== weight transpose =====================
DEV void tr_one(int i, const float* __restrict__ w, float* __restrict__ t, int cout, int cin) {
  int o = i / cin, c = i % cin;
  t[c * cout + o] = w[o * cin + c];
}
__global__ __launch_bounds__(256) void wt_all_kernel(
    const float* w00, const float* w01, const float* w02,
    const float* w10, const float* w11, const float* w12,
    float* t00, float* t01, float* t02, float* t10, float* t11, float* t12) {
  int i = blockIdx.x * 256 + threadIdx.x;
  if (i < 64 * 67) { tr_one(i, w00, t00, 64, 67); return; }
  i -= 64 * 67;
  if (i < 64 * 64) { tr_one(i, w01, t01, 64, 64); return; }
  i -= 64 * 64;
  if (i < 128 * 64) { tr_one(i, w02, t02, 128, 64); return; }
  i -= 128 * 64;
  if (i < 64 * 67) { tr_one(i, w10, t10, 64, 67); return; }
  i -= 64 * 67;
  if (i < 96 * 64) { tr_one(i, w11, t11, 96, 64); return; }
  i -= 96 * 64;
  if (i < 128 * 96) { tr_one(i, w12, t12, 128, 96); return; }
}

// ===================== MLP building blocks =====================
// lanes = 64 rows (K=32 packs 2 centers per tile); wid in [0,4); chunks of 8 channels.
template <int K>
DEV void load_x0(float* __restrict__ xin, const float* __restrict__ xyz,
                 const float* __restrict__ feat, const float* __restrict__ newxyz,
                 const int* __restrict__ idx, int tile) {
  constexpr int CIN0P = 69;
  constexpr int CPB = 64 / K;
  for (int i = threadIdx.x; i < 64 * CIN0; i += 256) {
    const int r = i & 63;
    const int c = i >> 6;  // 0..66
    const int rep = r / K;
    const int k = r % K;
    const int cs = tile * CPB + rep;
    const int b = cs >> 9;
    const int pi = idx[(size_t)cs * K + k];
    float v;
    if (c < 3) {
      v = xyz[((size_t)b * N_ + pi) * 3 + c] - newxyz[(size_t)cs * 3 + c];
    } else {
      v = feat[((size_t)b * CF_ + (c - 3)) * N_ + pi];
    }
    xin[r * CIN0P + c] = v;
  }
}

template <int CIN, int COUT>
DEV void gemm64(const float* xrow, const float* __restrict__ wt,
                const float* __restrict__ bias, int wid, float (*acc)[8]) {
  static_assert(COUT % 32 == 0, "COUT");
  constexpr int Q = COUT / 32;
#pragma unroll
  for (int q = 0; q < Q; ++q) {
    const int o0 = (q * 4 + wid) * 8;
#pragma unroll
    for (int j = 0; j < 8; ++j) acc[q][j] = bias[o0 + j];
  }
  for (int c = 0; c < CIN; ++c) {
    const float xv = xrow[c];
    const float* wr = wt + c * COUT;
#pragma unroll
    for (int q = 0; q < Q; ++q) {
      const int o0 = (q * 4 + wid) * 8;
      const float4 wa = *reinterpret_cast<const float4*>(wr + o0);
      const float4 wb = *reinterpret_cast<const float4*>(wr + o0 + 4);
      acc[q][0] += xv * wa.x; acc[q][1] += xv * wa.y;
      acc[q][2] += xv * wa.z; acc[q][3] += xv * wa.w;
      acc[q][4] += xv * wb.x; acc[q][5] += xv * wb.y;
      acc[q][6] += xv * wb.z; acc[q][7] += xv * wb.w;
    }
  }
}

template <int COUT, bool RELU>
DEV void norm_write(float* xout_row, const float* __restrict__ ac, int wid, float (*acc)[8]) {
  constexpr int Q = COUT / 32;
#pragma unroll
  for (int q = 0; q < Q; ++q) {
    const int o0 = (q * 4 + wid) * 8;
#pragma unroll
    for (int j = 0; j < 8; ++j) {
      float v = ac[o0 + j] * acc[q][j] + ac[COUT + o0 + j];
      if (RELU) v = v > 0.f ? v : 0.f;
      xout_row[o0 + j] = v;
    }
  }
}

template <int COUT>
DEV void stats_acc(float (*acc)[8], float (*ssum)[8], float (*ssq)[8]) {
  constexpr int Q = COUT / 32;
#pragma unroll
  for (int q = 0; q < Q; ++q)
#pragma unroll
    for (int j = 0; j < 8; ++j) {
      ssum[q][j] += acc[q][j];
      ssq[q][j] += acc[q][j] * acc[q][j];
    }
}

template <int COUT>
DEV void stats_flush(float (*ssum)[8], float (*ssq)[8], int wid, int lane,
                     float* __restrict__ stats_g) {
  constexpr int Q = COUT / 32;
#pragma unroll
  for (int q = 0; q < Q; ++q) {
#pragma unroll
    for (int j = 0; j < 8; ++j) {
      float s = ssum[q][j], s2 = ssq[q][j];
#pragma unroll
      for (int m = 1; m < 64; m <<= 1) {
        s += __shfl_xor(s, m);
        s2 += __shfl_xor(s2, m);
      }
      if (lane == 0) {
        const int o0 = (q * 4 + wid) * 8;
        atomicAdd(&stats_g[o0 + j], s);
        atomicAdd(&stats_g[COUT + o0 + j], s2);
      }
    }
  }
}

template <int COUT, int K>
DEV void max_write(float (*acc)[8], int wid, int lane, int tile, float* __restrict__ maxtmp) {
  constexpr int Q = COUT / 32;
#pragma unroll
  for (int q = 0; q < Q; ++q) {
    float m[8];
#pragma unroll
    for (int j = 0; j < 8; ++j) {
      float v = acc[q][j];
#pragma unroll
      for (int s = 1; s < K; s <<= 1) {
        float o = __shfl_xor(v, s);
        v = o > v ? o : v;
      }
      m[j] = v;
    }
    const int rep = lane / K;
    const int cs = tile * (64 / K) + rep;
    if ((lane % K) == 0) {
      const int o0 = (q * 4 + wid) * 8;
#pragma unroll
      for (int j = 0; j < 8; ++j) maxtmp[(size_t)cs * COUT + o0 + j] = m[j];
    }
  }
}

// STAGE 1: y0 stats. STAGE 2: y0->norm/relu->y1 stats. STAGE 3: ->y2 stats + max.
template <int K, int D0, int D1, int D2, int STAGE>
__global__ __launch_bounds__(256) void stage_kernel(
    const float* __restrict__ xyz, const float* __restrict__ feat,
    const float* __restrict__ newxyz, const int* __restrict__ idx,
    const float* __restrict__ wt0, const float* __restrict__ b0,
    const float* __restrict__ wt1, const float* __restrict__ b1,
    const float* __restrict__ wt2, const float* __restrict__ b2,
    const float* __restrict__ ac0, const float* __restrict__ ac1,
    float* __restrict__ stats_out, float* __restrict__ maxtmp) {
  constexpr int CIN0P = 69;
  constexpr int D0P = D0 + 1, D1P = D1 + 1;
  constexpr int CPB = 64 / K;
  constexpr int NT = (B_ * S_) / CPB;
  constexpr int BUFA = (STAGE == 3 && D1P > CIN0P) ? D1P : CIN0P;
  __shared__ float sA[64 * BUFA];
  __shared__ float sB[(STAGE >= 2) ? 64 * D0P : 1];

  const int t = threadIdx.x;
  const int lane = t & 63;
  const int wid = rfl(t >> 6);

  constexpr int DS = (STAGE == 1) ? D0 : (STAGE == 2) ? D1 : D2;
  constexpr int QS = DS / 32;
  float ssum[QS][8], ssq[QS][8];
#pragma unroll
  for (int q = 0; q < QS; ++q)
#pragma unroll
    for (int j = 0; j < 8; ++j) { ssum[q][j] = 0.f; ssq[q][j] = 0.f; }

  for (int tile = blockIdx.x; tile < NT; tile += gridDim.x) {
    __syncthreads();  // protect sA/sB reuse from previous tile
    load_x0<K>(sA, xyz, feat, newxyz, idx, tile);
    __syncthreads();
    float acc0[D0 / 32][8];
    gemm64<CIN0, D0>(sA + lane * CIN0P, wt0, b0, wid, acc0);
    if (STAGE == 1) {
      stats_acc<D0>(acc0, ssum, ssq);
    } else {
      norm_write<D0, true>(sB + lane * D0P, ac0, wid, acc0);
      __syncthreads();
      float acc1[D1 / 32][8];
      gemm64<D0, D1>(sB + lane * D0P, wt1, b1, wid, acc1);
      if (STAGE == 2) {
        stats_acc<D1>(acc1, ssum, ssq);
      } else {
        __syncthreads();  // all GEMM1 sB reads done before sA overwrite? (sA!=sB, but ensure GEMM0 readers done long ago; this also orders next write)
        norm_write<D1, true>(sA + lane * D1P, ac1, wid, acc1);
        __syncthreads();
        float acc2[D2 / 32][8];
        gemm64<D1, D2>(sA + lane * D1P, wt2, b2, wid, acc2);
        stats_acc<D2>(acc2, ssum, ssq);
        max_write<D2, K>(acc2, wid, lane, tile, maxtmp);
      }
    }
  }
  stats_flush<DS>(ssum, ssq, wid, lane, stats_out);
}

__global__ void finalize_kernel(const float* __restrict__ stats, const float* __restrict__ g,
                                const float* __restrict__ beta, float* __restrict__ ac,
                                float n, int cout) {
  const int t = threadIdx.x;
  if (t < cout) {
    const float mu = stats[t] / n;
    const float var = stats[cout + t] / n - mu * mu;
    const float a = g[t] / sqrtf(var + EPS_);
    ac[t] = a;
    ac[cout + t] = beta[t] - mu * a;
  }
}

__global__ __launch_bounds__(256) void out_kernel(const float* __restrict__ maxtmp,
                                                  const float* __restrict__ ac2,
                                                  float* __restrict__ outf, int coff) {
  const int i = blockIdx.x * 256 + threadIdx.x;  // (b*128+o)*512+s
  if (i >= B_ * 128 * S_) return;
  const int s = i & 511;
  const int o = (i >> 9) & 127;
  const int b = i >> 16;
  const float a = ac2[o], c = ac2[128 + o];
  const float v = maxtmp[((size_t)(b * S_ + s)) * 128 + o];
  outf[((size_t)b * 256 + coff + o) * S_ + s] = a * v + c;
}

}  // namespace

extern "C" void kernel_launch(void* const* d_in, const int* in_sizes, int n_in,
                              void* d_out, int out_size, void* d_ws, size_t ws_size,
                              hipStream_t stream) {
  const float* xyz = (const float*)d_in[0];
  const float* feat = (const float*)d_in[1];
  const float* w00 = (const float*)d_in[2];
  const float* b00 = (const float*)d_in[3];
  const float* g00 = (const float*)d_in[4];
  const float* be00 = (const float*)d_in[5];
  const float* w01 = (const float*)d_in[6];
  const float* b01 = (const float*)d_in[7];
  const float* g01 = (const float*)d_in[8];
  const float* be01 = (const float*)d_in[9];
  const float* w02 = (const float*)d_in[10];
  const float* b02 = (const float*)d_in[11];
  const float* g02 = (const float*)d_in[12];
  const float* be02 = (const float*)d_in[13];
  const float* w10 = (const float*)d_in[14];
  const float* b10 = (const float*)d_in[15];
  const float* g10 = (const float*)d_in[16];
  const float* be10 = (const float*)d_in[17];
  const float* w11 = (const float*)d_in[18];
  const float* b11 = (const float*)d_in[19];
  const float* g11 = (const float*)d_in[20];
  const float* be11 = (const float*)d_in[21];
  const float* w12 = (const float*)d_in[22];
  const float* b12 = (const float*)d_in[23];
  const float* g12 = (const float*)d_in[24];
  const float* be12 = (const float*)d_in[25];

  float* ws = (float*)d_ws;
  int* fpsidx = (int*)(ws + FPSIDX_OFF);
  int* idx0 = (int*)(ws + IDX0_OFF);
  int* idx1 = (int*)(ws + IDX1_OFF);
  float* stats = ws + STATS_OFF;
  float* ac = ws + AC_OFF;
  float* t00 = ws + WT00_OFF;
  float* t01 = ws + WT01_OFF;
  float* t02 = ws + WT02_OFF;
  float* t10 = ws + WT10_OFF;
  float* t11 = ws + WT11_OFF;
  float* t12 = ws + WT12_OFF;
  float* maxtmp = ws + MAXT_OFF;

  float* outF = (float*)d_out;           // new_xyz (B,S,3)
  float* outFeat = outF + B_ * S_ * 3;   // (B,256,S)

  hipMemsetAsync(stats, 0, 6 * 256 * sizeof(float), stream);
  wt_all_kernel<<<154, 256, 0, stream>>>(w00, w01, w02, w10, w11, w12,
                                         t00, t01, t02, t10, t11, t12);
  fps_kernel<<<16, 1024, 0, stream>>>(xyz, fpsidx, outF);
  ballq_kernel<32><<<2048, 256, 0, stream>>>(xyz, outF, idx0, 0.2f * 0.2f);
  ballq_kernel<64><<<2048, 256, 0, stream>>>(xyz, outF, idx1, 0.4f * 0.4f);

  const float n0 = (float)(B_ * S_ * 32);
  const float n1 = (float)(B_ * S_ * 64);

  // ---- scale 0: K=32, 67->64->64->128 ----
  stage_kernel<32, 64, 64, 128, 1><<<2048, 256, 0, stream>>>(
      xyz, feat, outF, idx0, t00, b00, t01, b01, t02, b02,
      ac + 0 * 256, ac + 1 * 256, stats + 0 * 256, maxtmp);
  finalize_kernel<<<1, 128, 0, stream>>>(stats + 0 * 256, g00, be00, ac + 0 * 256, n0, 64);
  stage_kernel<32, 64, 64, 128, 2><<<2048, 256, 0, stream>>>(
      xyz, feat, outF, idx0, t00, b00, t01, b01, t02, b02,
      ac + 0 * 256, ac + 1 * 256, stats + 1 * 256, maxtmp);
  finalize_kernel<<<1, 128, 0, stream>>>(stats + 1 * 256, g01, be01, ac + 1 * 256, n0, 64);
  stage_kernel<32, 64, 64, 128, 3><<<2048, 256, 0, stream>>>(
      xyz, feat, outF, idx0, t00, b00, t01, b01, t02, b02,
      ac + 0 * 256, ac + 1 * 256, stats + 2 * 256, maxtmp);
  finalize_kernel<<<1, 128, 0, stream>>>(stats + 2 * 256, g02, be02, ac + 2 * 256, n0, 128);
  out_kernel<<<4096, 256, 0, stream>>>(maxtmp, ac + 2 * 256, outFeat, 0);

  // ---- scale 1: K=64, 67->64->96->128 ----
  stage_kernel<64, 64, 96, 128, 1><<<2048, 256, 0, stream>>>(
      xyz, feat, outF, idx1, t10, b10, t11, b11, t12, b12,
      ac + 3 * 256, ac + 4 * 256, stats + 3 * 256, maxtmp);
  finalize_kernel<<<1, 128, 0, stream>>>(stats + 3 * 256, g10, be10, ac + 3 * 256, n1, 64);
  stage_kernel<64, 64, 96, 128, 2><<<2048, 256, 0, stream>>>(
      xyz, feat, outF, idx1, t10, b10, t11, b11, t12, b12,
      ac + 3 * 256, ac + 4 * 256, stats + 4 * 256, maxtmp);
  finalize_kernel<<<1, 128, 0, stream>>>(stats + 4 * 256, g11, be11, ac + 4 * 256, n1, 96);
  stage_kernel<64, 64, 96, 128, 3><<<2048, 256, 0, stream>>>(
      xyz, feat, outF, idx1, t10, b10, t11, b11, t12, b12,
      ac + 3 * 256, ac + 4 * 256, stats + 5 * 256, maxtmp);
  finalize_kernel<<<1, 128, 0, stream>>>(stats + 5 * 256, g12, be12, ac + 5 * 256, n1, 128);
  out_kernel<<<4096, 256, 0, stream>>>(maxtmp, ac + 5 * 256, outFeat, 128);
}

// Round 2
// 2118.970 us; speedup vs baseline: 3.0745x; 3.0745x over previous
//
#include <hip/hip_runtime.h>

#define DEV __device__ __forceinline__

namespace {

typedef __attribute__((ext_vector_type(8))) short short8;
typedef __attribute__((ext_vector_type(4))) float f32x4;

constexpr int B_ = 16, N_ = 4096, S_ = 512, CF_ = 64;
constexpr float EPS_ = 1e-5f;

// ---- ws layout (float units) ----
constexpr int IDX0_OFF  = 0;                    // B*S*32 ints
constexpr int IDX1_OFF  = 262144;               // B*S*64 ints
constexpr int STATS_OFF = IDX1_OFF + 524288;    // 6*256 f
constexpr int AC_OFF    = STATS_OFF + 1536;     // 6*256 f
constexpr int WP_OFF    = AC_OFF + 1536;        // 43008 ushorts = 21504 f
constexpr int MAXT_OFF  = WP_OFF + 21504;       // 8192*128 f
constexpr int FEATT_OFF = MAXT_OFF + 1048576;   // 4194304 ushorts = 2097152 f
constexpr size_t WS_NEED_FT = (size_t)(FEATT_OFF + 2097152) * 4;

// packed-weight sub-offsets (ushort units)
constexpr int WP00 = 0,     WP01 = 6144,  WP02 = 10240;
constexpr int WP10 = 18432, WP11 = 24576, WP12 = 30720;

DEV int rfl(int x) { return __builtin_amdgcn_readfirstlane(x); }

DEV unsigned short f2bf(float x) {  // RNE float->bf16
  unsigned u = __float_as_uint(x);
  u += 0x7fff + ((u >> 16) & 1);
  return (unsigned short)(u >> 16);
}

// ===================== FPS =====================
__global__ __launch_bounds__(1024) void fps_kernel(const float* __restrict__ xyz,
                                                   float* __restrict__ newxyz) {
  __shared__ float px[N_], py[N_], pz[N_];
  __shared__ float swv[16];
  __shared__ int   swi[16];
  __shared__ int   s_last;
  const int b = blockIdx.x, t = threadIdx.x;
  const float* xb = xyz + (size_t)b * N_ * 3;
  for (int i = t; i < N_; i += 1024) {
    px[i] = xb[i * 3 + 0];
    py[i] = xb[i * 3 + 1];
    pz[i] = xb[i * 3 + 2];
  }
  __syncthreads();
  float dr[4] = {1e10f, 1e10f, 1e10f, 1e10f};
  int last = 0;
  if (t == 0) {
    newxyz[(size_t)(b * S_ + 0) * 3 + 0] = px[0];
    newxyz[(size_t)(b * S_ + 0) * 3 + 1] = py[0];
    newxyz[(size_t)(b * S_ + 0) * 3 + 2] = pz[0];
  }
  for (int it = 1; it < S_; ++it) {
    const float cx = px[last], cy = py[last], cz = pz[last];
    float bv = -1.0f;
    int bi = 0x7fffffff;
#pragma unroll
    for (int j = 0; j < 4; ++j) {
      const int i = t + j * 1024;
      float d;
      {
#pragma clang fp contract(off)
        float dx = px[i] - cx, dy = py[i] - cy, dz = pz[i] - cz;
        d = (dx * dx + dy * dy) + dz * dz;
      }
      float dm = dr[j] < d ? dr[j] : d;
      dr[j] = dm;
      if (dm > bv) { bv = dm; bi = i; }
    }
#pragma unroll
    for (int m = 1; m < 64; m <<= 1) {
      float ov = __shfl_xor(bv, m);
      int   oi = __shfl_xor(bi, m);
      if (ov > bv || (ov == bv && oi < bi)) { bv = ov; bi = oi; }
    }
    if ((t & 63) == 0) { swv[t >> 6] = bv; swi[t >> 6] = bi; }
    __syncthreads();
    if (t < 64) {
      float v2 = (t < 16) ? swv[t] : -1.0f;
      int   i2 = (t < 16) ? swi[t] : 0x7fffffff;
#pragma unroll
      for (int m = 1; m < 16; m <<= 1) {
        float ov = __shfl_xor(v2, m);
        int   oi = __shfl_xor(i2, m);
        if (ov > v2 || (ov == v2 && oi < i2)) { v2 = ov; i2 = oi; }
      }
      if (t == 0) {
        s_last = i2;
        newxyz[(size_t)(b * S_ + it) * 3 + 0] = px[i2];
        newxyz[(size_t)(b * S_ + it) * 3 + 1] = py[i2];
        newxyz[(size_t)(b * S_ + it) * 3 + 2] = pz[i2];
      }
    }
    __syncthreads();
    last = s_last;
  }
}

// ===================== Ball query =====================
template <int NS>
__global__ __launch_bounds__(256) void ballq_kernel(const float* __restrict__ xyz,
                                                    const float* __restrict__ newxyz,
                                                    int* __restrict__ idx, float r2) {
  __shared__ int sbuf[4][NS];
  const int wiv = threadIdx.x >> 6;
  const int lane = threadIdx.x & 63;
  const int cs = blockIdx.x * 4 + wiv;
  const int b = cs >> 9;
  const float cx = newxyz[(size_t)cs * 3 + 0];
  const float cy = newxyz[(size_t)cs * 3 + 1];
  const float cz = newxyz[(size_t)cs * 3 + 2];
  const float* xb = xyz + (size_t)b * N_ * 3;
  int* my = sbuf[wiv];
  int cnt = 0;
  for (int base = 0; base < N_; base += 64) {
    if (cnt >= NS) break;
    const int i = base + lane;
    float d;
    {
#pragma clang fp contract(off)
      float dx = xb[i * 3 + 0] - cx, dy = xb[i * 3 + 1] - cy, dz = xb[i * 3 + 2] - cz;
      d = (dx * dx + dy * dy) + dz * dz;
    }
    const bool q = d < r2;
    const unsigned long long m = __ballot(q);
    if (q) {
      int pos = cnt + __popcll(m & ((1ull << lane) - 1ull));
      if (pos < NS) my[pos] = i;
    }
    cnt += __popcll(m);
  }
  __syncthreads();
  const int c = cnt < NS ? cnt : NS;
  const int first = my[0];
  for (int j = lane; j < NS; j += 64) idx[(size_t)cs * NS + j] = (j < c) ? my[j] : first;
}

// ===================== feat transpose to (B,N,64) bf16 =====================
__global__ __launch_bounds__(256) void featT_kernel(const float* __restrict__ feat,
                                                    unsigned short* __restrict__ featT) {
  __shared__ unsigned short tile[64][65];
  const int t = threadIdx.x;
  const int b = blockIdx.x >> 6, nc = blockIdx.x & 63;
  const int n0 = nc * 64;
  for (int i = t; i < 64 * 64; i += 256) {
    int c = i >> 6, n = i & 63;
    tile[c][n] = f2bf(feat[((size_t)b * CF_ + c) * N_ + n0 + n]);
  }
  __syncthreads();
  for (int i = t; i < 64 * 64; i += 256) {
    int n = i >> 6, c = i & 63;
    featT[((size_t)b * N_ + n0 + n) * 64 + c] = tile[c][n];
  }
}

// ===================== weight pack into B-fragment order =====================
// layout per layer: [ntile][kk][lane][8], value = W[ntile*16+(l&15)][perm(kk*32+(l>>4)*8+j)]
__global__ __launch_bounds__(256) void pack_w_kernel(
    const float* __restrict__ w00, const float* __restrict__ w01, const float* __restrict__ w02,
    const float* __restrict__ w10, const float* __restrict__ w11, const float* __restrict__ w12,
    unsigned short* __restrict__ wp) {
  const int id = blockIdx.x * 256 + threadIdx.x;
  const float* w; int off, KK, CINW, base; bool perm;
  if (id < 768)       { w = w00; off = WP00; KK = 3; CINW = 67; perm = true;  base = 0; }
  else if (id < 1280) { w = w01; off = WP01; KK = 2; CINW = 64; perm = false; base = 768; }
  else if (id < 2304) { w = w02; off = WP02; KK = 2; CINW = 64; perm = false; base = 1280; }
  else if (id < 3072) { w = w10; off = WP10; KK = 3; CINW = 67; perm = true;  base = 2304; }
  else if (id < 3840) { w = w11; off = WP11; KK = 2; CINW = 64; perm = false; base = 3072; }
  else if (id < 5376) { w = w12; off = WP12; KK = 3; CINW = 96; perm = false; base = 3840; }
  else return;
  const int lid = id - base;
  const int lane = lid & 63, fr = lid >> 6;
  const int kk = fr % KK, nt = fr / KK;
  const int ccol = nt * 16 + (lane & 15);
  const int kbase = kk * 32 + (lane >> 4) * 8;
  unsigned short* dst = wp + off + (size_t)lid * 8;
#pragma unroll
  for (int j = 0; j < 8; ++j) {
    const int k = kbase + j;
    int cin;
    if (perm) cin = (k < 64) ? k + 3 : (k < 67 ? k - 64 : -1);
    else      cin = (k < CINW) ? k : -1;
    float f = (cin >= 0) ? w[ccol * CINW + cin] : 0.f;
    dst[j] = f2bf(f);
  }
}

// ===================== MFMA stage =====================
// X layout in LDS: cols 0..63 = feat channels, 64..66 = xyz diff, 67.. = zero pad.
template <int K, bool FT>
DEV void gather_tile(unsigned short* sX, const float* __restrict__ xyz,
                     const float* __restrict__ feat, const unsigned short* __restrict__ featT,
                     const float* __restrict__ newxyz, const int* __restrict__ idx, int tile) {
  const int t = threadIdx.x, r = t & 63, c4 = t >> 6;
  const int rep = r / K, k = r % K;
  const int cs = tile * (64 / K) + rep, b = cs >> 9;
  const int pi = idx[(size_t)cs * K + k];
  unsigned short* dst = sX + r * 104;
  if (FT) {
    const unsigned short* src = featT + (((size_t)b * N_ + pi) << 6) + c4 * 16;
    *reinterpret_cast<short8*>(dst + c4 * 16)     = *reinterpret_cast<const short8*>(src);
    *reinterpret_cast<short8*>(dst + c4 * 16 + 8) = *reinterpret_cast<const short8*>(src + 8);
  } else {
#pragma unroll
    for (int j = 0; j < 16; ++j) {
      const int ch = c4 * 16 + j;
      dst[ch] = f2bf(feat[((size_t)b * CF_ + ch) * N_ + pi]);
    }
  }
  if (c4 == 0) {
    const float* P = xyz + ((size_t)b * N_ + pi) * 3;
    const float* C = newxyz + (size_t)cs * 3;
    dst[64] = f2bf(P[0] - C[0]);
    dst[65] = f2bf(P[1] - C[1]);
    dst[66] = f2bf(P[2] - C[2]);
  }
}

template <int NTILES, int KK>
DEV void layer_mfma(const unsigned short* sIn, int stride, const unsigned short* __restrict__ wp,
                    int lane, int wid, f32x4* acc) {
  short8 af[KK];
  const int arow = wid * 16 + (lane & 15);
  const int kof = (lane >> 4) * 8;
#pragma unroll
  for (int kk = 0; kk < KK; ++kk)
    af[kk] = *reinterpret_cast<const short8*>(sIn + arow * stride + kk * 32 + kof);
#pragma unroll
  for (int nt = 0; nt < NTILES; ++nt) {
    f32x4 a = {0.f, 0.f, 0.f, 0.f};
#pragma unroll
    for (int kk = 0; kk < KK; ++kk) {
      short8 bf = *reinterpret_cast<const short8*>(wp + ((size_t)(nt * KK + kk) * 64 + lane) * 8);
      a = __builtin_amdgcn_mfma_f32_16x16x32_bf16(af[kk], bf, a, 0, 0, 0);
    }
    acc[nt] = a;
  }
}

template <int K, int D0, int D1, int D2, int STAGE, bool FT>
__global__ __launch_bounds__(256) void stage_mfma(
    const float* __restrict__ xyz, const float* __restrict__ feat,
    const unsigned short* __restrict__ featT, const float* __restrict__ newxyz,
    const int* __restrict__ idx,
    const unsigned short* __restrict__ wp0, const unsigned short* __restrict__ wp1,
    const unsigned short* __restrict__ wp2,
    const float* __restrict__ b0, const float* __restrict__ b1, const float* __restrict__ b2,
    const float* __restrict__ ac0, const float* __restrict__ ac1,
    float* __restrict__ stats_out, float* __restrict__ maxtmp) {
  constexpr int CPB = 64 / K, NT = (B_ * S_) / CPB;
  constexpr int ST0 = 104, ST1 = 72, ST2 = (D1 == 96) ? 104 : 72;
  constexpr int KK0 = 3, KK1 = D0 / 32, KK2 = D1 / 32;
  constexpr int NT0 = D0 / 16, NT1 = D1 / 16, NT2 = D2 / 16;
  constexpr int DS = (STAGE == 1) ? D0 : (STAGE == 2) ? D1 : D2;
  constexpr int NTS = DS / 16;

  __shared__ unsigned short sX[64 * ST0];
  __shared__ unsigned short sY0[(STAGE >= 2) ? 64 * ST1 : 8];
  __shared__ unsigned short sY1[(STAGE == 3) ? 64 * ST2 : 8];
  __shared__ float smax[(STAGE == 3) ? 512 : 4];

  const int t = threadIdx.x, lane = t & 63;
  const int wid = rfl(t >> 6);
  const int col = lane & 15, khi = lane >> 4;

  // zero X pad cols (67..103) once; gather never touches them afterwards
  for (int i = t; i < 64 * 37; i += 256) sX[(i / 37) * ST0 + 67 + (i % 37)] = 0;

  float b0r[NT0], a0r[NT0], c0r[NT0];
  float b1r[NT1], a1r[NT1], c1r[NT1];
  float b2r[NT2];
#pragma unroll
  for (int nt = 0; nt < NT0; ++nt) {
    b0r[nt] = b0[nt * 16 + col];
    if constexpr (STAGE >= 2) {
      a0r[nt] = ac0[nt * 16 + col];
      c0r[nt] = ac0[D0 + nt * 16 + col];
    }
  }
  if constexpr (STAGE >= 2) {
#pragma unroll
    for (int nt = 0; nt < NT1; ++nt) {
      b1r[nt] = b1[nt * 16 + col];
      if constexpr (STAGE == 3) {
        a1r[nt] = ac1[nt * 16 + col];
        c1r[nt] = ac1[D1 + nt * 16 + col];
      }
    }
  }
  if constexpr (STAGE == 3) {
#pragma unroll
    for (int nt = 0; nt < NT2; ++nt) b2r[nt] = b2[nt * 16 + col];
  }

  float ssum[NTS], ssq[NTS];
#pragma unroll
  for (int nt = 0; nt < NTS; ++nt) { ssum[nt] = 0.f; ssq[nt] = 0.f; }

  for (int tile = blockIdx.x; tile < NT; tile += gridDim.x) {
    __syncthreads();
    gather_tile<K, FT>(sX, xyz, feat, featT, newxyz, idx, tile);
    __syncthreads();

    f32x4 acc0[NT0];
    layer_mfma<NT0, KK0>(sX, ST0, wp0, lane, wid, acc0);
    if constexpr (STAGE == 1) {
#pragma unroll
      for (int nt = 0; nt < NT0; ++nt) {
        const float bb = b0r[nt];
#pragma unroll
        for (int j = 0; j < 4; ++j) {
          const float y = acc0[nt][j] + bb;
          ssum[nt] += y; ssq[nt] += y * y;
        }
      }
    } else {
#pragma unroll
      for (int nt = 0; nt < NT0; ++nt) {
#pragma unroll
        for (int j = 0; j < 4; ++j) {
          float y = (acc0[nt][j] + b0r[nt]) * a0r[nt] + c0r[nt];
          y = fmaxf(y, 0.f);
          sY0[(wid * 16 + khi * 4 + j) * ST1 + nt * 16 + col] = f2bf(y);
        }
      }
      __syncthreads();
      f32x4 acc1[NT1];
      layer_mfma<NT1, KK1>(sY0, ST1, wp1, lane, wid, acc1);
      if constexpr (STAGE == 2) {
#pragma unroll
        for (int nt = 0; nt < NT1; ++nt) {
          const float bb = b1r[nt];
#pragma unroll
          for (int j = 0; j < 4; ++j) {
            const float y = acc1[nt][j] + bb;
            ssum[nt] += y; ssq[nt] += y * y;
          }
        }
      } else {
#pragma unroll
        for (int nt = 0; nt < NT1; ++nt) {
#pragma unroll
          for (int j = 0; j < 4; ++j) {
            float y = (acc1[nt][j] + b1r[nt]) * a1r[nt] + c1r[nt];
            y = fmaxf(y, 0.f);
            sY1[(wid * 16 + khi * 4 + j) * ST2 + nt * 16 + col] = f2bf(y);
          }
        }
        __syncthreads();
        f32x4 acc2[NT2];
        layer_mfma<NT2, KK2>(sY1, ST2, wp2, lane, wid, acc2);
#pragma unroll
        for (int nt = 0; nt < NT2; ++nt) {
          const float bb = b2r[nt];
          const float y0 = acc2[nt][0] + bb, y1 = acc2[nt][1] + bb;
          const float y2 = acc2[nt][2] + bb, y3 = acc2[nt][3] + bb;
          ssum[nt] += (y0 + y1) + (y2 + y3);
          ssq[nt] += (y0 * y0 + y1 * y1) + (y2 * y2 + y3 * y3);
          float m = fmaxf(fmaxf(y0, y1), fmaxf(y2, y3));
          m = fmaxf(m, __shfl_xor(m, 16));
          m = fmaxf(m, __shfl_xor(m, 32));
          if (lane < 16) smax[wid * 128 + nt * 16 + lane] = m;
        }
        __syncthreads();
        if constexpr (K == 64) {
          if (t < 128) {
            const float m = fmaxf(fmaxf(smax[t], smax[128 + t]), fmaxf(smax[256 + t], smax[384 + t]));
            maxtmp[(size_t)tile * 128 + t] = m;
          }
        } else {
          const int ce = t >> 7, ch = t & 127;
          const float m = fmaxf(smax[ce * 256 + ch], smax[ce * 256 + 128 + ch]);
          maxtmp[((size_t)(tile * 2 + ce)) * 128 + ch] = m;
        }
      }
    }
  }

#pragma unroll
  for (int nt = 0; nt < NTS; ++nt) {
    float s = ssum[nt], q = ssq[nt];
    s += __shfl_xor(s, 16); q += __shfl_xor(q, 16);
    s += __shfl_xor(s, 32); q += __shfl_xor(q, 32);
    if (lane < 16) {
      atomicAdd(&stats_out[nt * 16 + lane], s);
      atomicAdd(&stats_out[DS + nt * 16 + lane], q);
    }
  }
}

__global__ void finalize_kernel(const float* __restrict__ stats, const float* __restrict__ g,
                                const float* __restrict__ beta, float* __restrict__ ac,
                                float n, int cout) {
  const int t = threadIdx.x;
  if (t < cout) {
    const float mu = stats[t] / n;
    const float var = stats[cout + t] / n - mu * mu;
    const float a = g[t] / sqrtf(var + EPS_);
    ac[t] = a;
    ac[cout + t] = beta[t] - mu * a;
  }
}

__global__ __launch_bounds__(256) void out_kernel(const float* __restrict__ maxtmp,
                                                  const float* __restrict__ ac2,
                                                  float* __restrict__ outf, int coff) {
  const int i = blockIdx.x * 256 + threadIdx.x;
  if (i >= B_ * 128 * S_) return;
  const int s = i & 511;
  const int o = (i >> 9) & 127;
  const int b = i >> 16;
  const float a = ac2[o], c = ac2[128 + o];
  const float v = maxtmp[((size_t)(b * S_ + s)) * 128 + o];
  outf[((size_t)b * 256 + coff + o) * S_ + s] = a * v + c;
}

}  // namespace

extern "C" void kernel_launch(void* const* d_in, const int* in_sizes, int n_in,
                              void* d_out, int out_size, void* d_ws, size_t ws_size,
                              hipStream_t stream) {
  const float* xyz  = (const float*)d_in[0];
  const float* feat = (const float*)d_in[1];
  const float* w00 = (const float*)d_in[2];  const float* b00 = (const float*)d_in[3];
  const float* g00 = (const float*)d_in[4];  const float* be00 = (const float*)d_in[5];
  const float* w01 = (const float*)d_in[6];  const float* b01 = (const float*)d_in[7];
  const float* g01 = (const float*)d_in[8];  const float* be01 = (const float*)d_in[9];
  const float* w02 = (const float*)d_in[10]; const float* b02 = (const float*)d_in[11];
  const float* g02 = (const float*)d_in[12]; const float* be02 = (const float*)d_in[13];
  const float* w10 = (const float*)d_in[14]; const float* b10 = (const float*)d_in[15];
  const float* g10 = (const float*)d_in[16]; const float* be10 = (const float*)d_in[17];
  const float* w11 = (const float*)d_in[18]; const float* b11 = (const float*)d_in[19];
  const float* g11 = (const float*)d_in[20]; const float* be11 = (const float*)d_in[21];
  const float* w12 = (const float*)d_in[22]; const float* b12 = (const float*)d_in[23];
  const float* g12 = (const float*)d_in[24]; const float* be12 = (const float*)d_in[25];

  float* ws = (float*)d_ws;
  int* idx0 = (int*)(ws + IDX0_OFF);
  int* idx1 = (int*)(ws + IDX1_OFF);
  float* stats = ws + STATS_OFF;
  float* ac = ws + AC_OFF;
  unsigned short* wp = (unsigned short*)(ws + WP_OFF);
  float* maxtmp = ws + MAXT_OFF;
  unsigned short* featT = (unsigned short*)(ws + FEATT_OFF);

  const bool useFT = ws_size >= WS_NEED_FT;

  float* outF = (float*)d_out;          // new_xyz (B,S,3)
  float* outFeat = outF + B_ * S_ * 3;  // (B,256,S)

  hipMemsetAsync(stats, 0, 6 * 256 * sizeof(float), stream);
  pack_w_kernel<<<21, 256, 0, stream>>>(w00, w01, w02, w10, w11, w12, wp);
  if (useFT) featT_kernel<<<1024, 256, 0, stream>>>(feat, featT);
  fps_kernel<<<16, 1024, 0, stream>>>(xyz, outF);
  ballq_kernel<32><<<2048, 256, 0, stream>>>(xyz, outF, idx0, 0.2f * 0.2f);
  ballq_kernel<64><<<2048, 256, 0, stream>>>(xyz, outF, idx1, 0.4f * 0.4f);

  const float n0 = (float)(B_ * S_ * 32);
  const float n1 = (float)(B_ * S_ * 64);

#define LAUNCH_SCALE0(STG)                                                              \
  do {                                                                                  \
    if (useFT)                                                                          \
      stage_mfma<32, 64, 64, 128, STG, true><<<2048, 256, 0, stream>>>(                 \
          xyz, feat, featT, outF, idx0, wp + WP00, wp + WP01, wp + WP02, b00, b01, b02, \
          ac + 0 * 256, ac + 1 * 256, stats + (STG - 1) * 256, maxtmp);                 \
    else                                                                                \
      stage_mfma<32, 64, 64, 128, STG, false><<<2048, 256, 0, stream>>>(                \
          xyz, feat, featT, outF, idx0, wp + WP00, wp + WP01, wp + WP02, b00, b01, b02, \
          ac + 0 * 256, ac + 1 * 256, stats + (STG - 1) * 256, maxtmp);                 \
  } while (0)
#define LAUNCH_SCALE1(STG)                                                              \
  do {                                                                                  \
    if (useFT)                                                                          \
      stage_mfma<64, 64, 96, 128, STG, true><<<2048, 256, 0, stream>>>(                 \
          xyz, feat, featT, outF, idx1, wp + WP10, wp + WP11, wp + WP12, b10, b11, b12, \
          ac + 3 * 256, ac + 4 * 256, stats + (2 + STG) * 256, maxtmp);                 \
    else                                                                                \
      stage_mfma<64, 64, 96, 128, STG, false><<<2048, 256, 0, stream>>>(                \
          xyz, feat, featT, outF, idx1, wp + WP10, wp + WP11, wp + WP12, b10, b11, b12, \
          ac + 3 * 256, ac + 4 * 256, stats + (2 + STG) * 256, maxtmp);                 \
  } while (0)

  // ---- scale 0: K=32, 67->64->64->128 ----
  LAUNCH_SCALE0(1);
  finalize_kernel<<<1, 128, 0, stream>>>(stats + 0 * 256, g00, be00, ac + 0 * 256, n0, 64);
  LAUNCH_SCALE0(2);
  finalize_kernel<<<1, 128, 0, stream>>>(stats + 1 * 256, g01, be01, ac + 1 * 256, n0, 64);
  LAUNCH_SCALE0(3);
  finalize_kernel<<<1, 128, 0, stream>>>(stats + 2 * 256, g02, be02, ac + 2 * 256, n0, 128);
  out_kernel<<<4096, 256, 0, stream>>>(maxtmp, ac + 2 * 256, outFeat, 0);

  // ---- scale 1: K=64, 67->64->96->128 ----
  LAUNCH_SCALE1(1);
  finalize_kernel<<<1, 128, 0, stream>>>(stats + 3 * 256, g10, be10, ac + 3 * 256, n1, 64);
  LAUNCH_SCALE1(2);
  finalize_kernel<<<1, 128, 0, stream>>>(stats + 4 * 256, g11, be11, ac + 4 * 256, n1, 96);
  LAUNCH_SCALE1(3);
  finalize_kernel<<<1, 128, 0, stream>>>(stats + 5 * 256, g12, be12, ac + 5 * 256, n1, 128);
  out_kernel<<<4096, 256, 0, stream>>>(maxtmp, ac + 5 * 256, outFeat, 128);

#undef LAUNCH_SCALE0
#undef LAUNCH_SCALE1
}